// Round 6
// baseline (308.368 us; speedup 1.0000x reference)
//
#include <hip/hip_runtime.h>

// Semantics (verified through R0-R9 of previous session):
//   ABI: tokens (N,D) fp32, coords (N,2) int32, weight (D,1,3,3) fp32,
//   straight taps, straight scatter, zero padding/empty cells, bias added,
//   OUTPUT IS (D, N) flat (np advanced indexing, missing .T).
// R15 (= R14 with compile fix): R2 geometry (74us: TPB=32, 256thr, 32KB LDS,
//   full-line epilogue)
//   + R3's explicit 2-deep gather pipeline (geometry unchanged, only
//     per-wave MLP raised; VGPR ~85 keeps the 20-wave/CU LDS cap binding).
//   + nontemporal epilogue stores via native ext_vector_type (HIP float4 is
//     a class; the builtin rejects it).
#define DD 256
#define HH 384
#define WW 384
#define NTOK 65536
#define TPB 32   // tokens per block
#define TPW 8    // tokens per wave

typedef float nfloat4 __attribute__((ext_vector_type(4)));

// ---------------------------------------------------------------------------
// Prep: weight (D,9) -> wT (9,D) (straight, no flip); bias copied.
// ---------------------------------------------------------------------------
__global__ __launch_bounds__(256) void prep_kernel(
    const float* __restrict__ weight, const float* __restrict__ bias,
    float* __restrict__ wT, float* __restrict__ biasf)
{
    int ch = threadIdx.x;  // 0..255
    #pragma unroll
    for (int k = 0; k < 9; ++k)
        wT[k * DD + ch] = weight[ch * 9 + k];
    biasf[ch] = bias[ch];
}

// ---------------------------------------------------------------------------
// Scatter (straight): pos_map[r*W + c] = token index (pre-filled with -1)
// ---------------------------------------------------------------------------
__global__ __launch_bounds__(256) void scatter_pos_kernel(
    const int* __restrict__ coords, int* __restrict__ pos_map)
{
    int n = blockIdx.x * blockDim.x + threadIdx.x;
    if (n < NTOK) {
        int r = coords[2 * n + 0];
        int c = coords[2 * n + 1];
        pos_map[r * WW + c] = n;
    }
}

// ---------------------------------------------------------------------------
// Main: 4 waves/block, 8 tokens per wave. Phase A: scalar (SMEM) loads of
// coords + all 72 pos_map entries (wave-uniform addresses). Phase B: 2-deep
// software-pipelined gather+FMA (18 x 1KB gathers in flight per wave).
// Epilogue: 32KB LDS transpose; thread ch stores a full 128B line
// out[ch*N + n0 .. n0+31] with nontemporal hint.
// ---------------------------------------------------------------------------
__global__ __launch_bounds__(256) void conv_gather_kernel(
    const float* __restrict__ tokens,
    const int*   __restrict__ coords,
    const float* __restrict__ wT,      // (9, D)
    const float* __restrict__ biasf,   // (D,)
    const int*   __restrict__ pos_map,
    float*       __restrict__ out)     // (D, N) layout!
{
    __shared__ float s_out[TPB][DD];            // 32 KB

    const int wave = threadIdx.x >> 6;          // 0..3
    const int lane = threadIdx.x & 63;
    const int c0   = lane * 4;
    // wave-uniform first token index, forced into SGPR
    const int nw   = __builtin_amdgcn_readfirstlane(blockIdx.x * TPB + wave * TPW);

    const float4 bias4 = *(const float4*)(biasf + c0);
    float4 w4[9];
    #pragma unroll
    for (int k = 0; k < 9; ++k)
        w4[k] = *(const float4*)(wT + k * DD + c0);

    // ---- Phase A: scalar loads. All addresses wave-uniform -> s_load. ----
    // midx holds token row, or (n | sign bit) when the tap is invalid.
    int midx[TPW][9];
    #pragma unroll
    for (int i = 0; i < TPW; ++i) {
        const int n = nw + i;
        const int r = coords[2 * n + 0];        // uniform -> s_load
        const int c = coords[2 * n + 1];
        #pragma unroll
        for (int dy = 0; dy < 3; ++dy) {
            #pragma unroll
            for (int dx = 0; dx < 3; ++dx) {
                const int k  = dy * 3 + dx;
                const int rr = r + dy - 1;
                const int cc = c + dx - 1;
                const bool in_bounds = (rr >= 0) & (rr < HH) & (cc >= 0) & (cc < WW);
                const int  pidx = in_bounds ? (rr * WW + cc) : 0;
                const int  m    = pos_map[pidx];    // uniform -> s_load
                const bool use  = in_bounds & (m >= 0);
                midx[i][k] = use ? m : (n | 0x80000000);  // self row, sel=0
            }
        }
    }

    // ---- Phase B: 2-deep software-pipelined gathers + FMA. ----
    float4 tbuf[2][9];
    float  sbuf[2][9];
    #pragma unroll
    for (int k = 0; k < 9; ++k) {
        const int mi = midx[0][k];
        tbuf[0][k] = *(const float4*)(tokens + (size_t)(mi & 0x7fffffff) * DD + c0);
        sbuf[0][k] = (mi >= 0) ? 1.0f : 0.0f;
    }
    #pragma unroll
    for (int i = 0; i < TPW; ++i) {
        const int cur = i & 1;
        const int nxt = cur ^ 1;
        if (i + 1 < TPW) {
            #pragma unroll
            for (int k = 0; k < 9; ++k) {
                const int mi = midx[i + 1][k];
                tbuf[nxt][k] = *(const float4*)(tokens + (size_t)(mi & 0x7fffffff) * DD + c0);
                sbuf[nxt][k] = (mi >= 0) ? 1.0f : 0.0f;
            }
        }
        float4 acc = bias4;
        #pragma unroll
        for (int k = 0; k < 9; ++k) {
            const float sel = sbuf[cur][k];
            acc.x += w4[k].x * (sel * tbuf[cur][k].x);
            acc.y += w4[k].y * (sel * tbuf[cur][k].y);
            acc.z += w4[k].z * (sel * tbuf[cur][k].z);
            acc.w += w4[k].w * (sel * tbuf[cur][k].w);
        }
        *(float4*)&s_out[wave * TPW + i][c0] = acc;
    }
    __syncthreads();

    // Thread ch gathers this block's 32 consecutive tokens for channel ch
    // and stores 128B contiguous at out[ch*N + n0], nontemporal (output is
    // never re-read; don't let it evict token rows from L2).
    const int ch = threadIdx.x;
    float* dst = out + (size_t)ch * NTOK + blockIdx.x * TPB;
    #pragma unroll
    for (int j = 0; j < 8; ++j) {
        nfloat4 v;
        v.x = s_out[4 * j + 0][ch];
        v.y = s_out[4 * j + 1][ch];
        v.z = s_out[4 * j + 2][ch];
        v.w = s_out[4 * j + 3][ch];
        __builtin_nontemporal_store(v, (nfloat4*)(dst + 4 * j));
    }
}

// ---------------------------------------------------------------------------
extern "C" void kernel_launch(void* const* d_in, const int* in_sizes, int n_in,
                              void* d_out, int out_size, void* d_ws, size_t ws_size,
                              hipStream_t stream)
{
    const float* tokens = (const float*)d_in[0];
    const int*   coords = (const int*)d_in[1];
    const float* weight = (const float*)d_in[2];
    const float* bias   = (const float*)d_in[3];
    float* out = (float*)d_out;

    // Workspace layout:
    //   [0, 9216)       wT: 9*256 fp32
    //   [9216, 10240)   biasf: 256 fp32
    //   [16384, 606208) pos_map: H*W int32
    char* ws = (char*)d_ws;
    float* wT      = (float*)ws;
    float* biasf   = (float*)(ws + 9216);
    int*   pos_map = (int*)(ws + 16384);

    hipMemsetAsync(pos_map, 0xFF, (size_t)HH * WW * sizeof(int), stream);
    prep_kernel<<<1, 256, 0, stream>>>(weight, bias, wT, biasf);
    scatter_pos_kernel<<<(NTOK + 255) / 256, 256, 0, stream>>>(coords, pos_map);
    conv_gather_kernel<<<NTOK / TPB, 256, 0, stream>>>(tokens, coords, wT, biasf,
                                                       pos_map, out);
}

// Round 7
// 175.562 us; speedup vs baseline: 1.7565x; 1.7565x over previous
//
#include <hip/hip_runtime.h>

// Semantics (verified through R0-R9 of previous session):
//   ABI: tokens (N,D) fp32, coords (N,2) int32, weight (D,1,3,3) fp32,
//   straight taps, straight scatter, zero padding/empty cells, bias added,
//   OUTPUT IS (D, N) flat (np advanced indexing, missing .T).
// R16: R2 geometry (74us: TPB=32, 256thr, 32KB LDS, full-line epilogue)
//   + 2-deep gather pipeline. NO nontemporal stores: R6 proved nt bypasses
//   L2 write-combining -> 2.7x write amplification (66->177MB), 74->217us.
//   The L2 IS the combining buffer for the 16B/thread epilogue stores.
#define DD 256
#define HH 384
#define WW 384
#define NTOK 65536
#define TPB 32   // tokens per block
#define TPW 8    // tokens per wave

// ---------------------------------------------------------------------------
// Prep: weight (D,9) -> wT (9,D) (straight, no flip); bias copied.
// ---------------------------------------------------------------------------
__global__ __launch_bounds__(256) void prep_kernel(
    const float* __restrict__ weight, const float* __restrict__ bias,
    float* __restrict__ wT, float* __restrict__ biasf)
{
    int ch = threadIdx.x;  // 0..255
    #pragma unroll
    for (int k = 0; k < 9; ++k)
        wT[k * DD + ch] = weight[ch * 9 + k];
    biasf[ch] = bias[ch];
}

// ---------------------------------------------------------------------------
// Scatter (straight): pos_map[r*W + c] = token index (pre-filled with -1)
// ---------------------------------------------------------------------------
__global__ __launch_bounds__(256) void scatter_pos_kernel(
    const int* __restrict__ coords, int* __restrict__ pos_map)
{
    int n = blockIdx.x * blockDim.x + threadIdx.x;
    if (n < NTOK) {
        int r = coords[2 * n + 0];
        int c = coords[2 * n + 1];
        pos_map[r * WW + c] = n;
    }
}

// ---------------------------------------------------------------------------
// Main: 4 waves/block, 8 tokens per wave. Phase A: scalar (SMEM) loads of
// coords + all 72 pos_map entries (wave-uniform addresses). Phase B: 2-deep
// software-pipelined gather+FMA (18 x 1KB gathers in flight per wave).
// Epilogue: 32KB LDS transpose; thread ch stores a full 128B line
// out[ch*N + n0 .. n0+31].
// ---------------------------------------------------------------------------
__global__ __launch_bounds__(256) void conv_gather_kernel(
    const float* __restrict__ tokens,
    const int*   __restrict__ coords,
    const float* __restrict__ wT,      // (9, D)
    const float* __restrict__ biasf,   // (D,)
    const int*   __restrict__ pos_map,
    float*       __restrict__ out)     // (D, N) layout!
{
    __shared__ float s_out[TPB][DD];            // 32 KB

    const int wave = threadIdx.x >> 6;          // 0..3
    const int lane = threadIdx.x & 63;
    const int c0   = lane * 4;
    // wave-uniform first token index, forced into SGPR
    const int nw   = __builtin_amdgcn_readfirstlane(blockIdx.x * TPB + wave * TPW);

    const float4 bias4 = *(const float4*)(biasf + c0);
    float4 w4[9];
    #pragma unroll
    for (int k = 0; k < 9; ++k)
        w4[k] = *(const float4*)(wT + k * DD + c0);

    // ---- Phase A: scalar loads. All addresses wave-uniform -> s_load. ----
    // midx holds token row, or (n | sign bit) when the tap is invalid.
    int midx[TPW][9];
    #pragma unroll
    for (int i = 0; i < TPW; ++i) {
        const int n = nw + i;
        const int r = coords[2 * n + 0];        // uniform -> s_load
        const int c = coords[2 * n + 1];
        #pragma unroll
        for (int dy = 0; dy < 3; ++dy) {
            #pragma unroll
            for (int dx = 0; dx < 3; ++dx) {
                const int k  = dy * 3 + dx;
                const int rr = r + dy - 1;
                const int cc = c + dx - 1;
                const bool in_bounds = (rr >= 0) & (rr < HH) & (cc >= 0) & (cc < WW);
                const int  pidx = in_bounds ? (rr * WW + cc) : 0;
                const int  m    = pos_map[pidx];    // uniform -> s_load
                const bool use  = in_bounds & (m >= 0);
                midx[i][k] = use ? m : (n | 0x80000000);  // self row, sel=0
            }
        }
    }

    // ---- Phase B: 2-deep software-pipelined gathers + FMA. ----
    float4 tbuf[2][9];
    float  sbuf[2][9];
    #pragma unroll
    for (int k = 0; k < 9; ++k) {
        const int mi = midx[0][k];
        tbuf[0][k] = *(const float4*)(tokens + (size_t)(mi & 0x7fffffff) * DD + c0);
        sbuf[0][k] = (mi >= 0) ? 1.0f : 0.0f;
    }
    #pragma unroll
    for (int i = 0; i < TPW; ++i) {
        const int cur = i & 1;
        const int nxt = cur ^ 1;
        if (i + 1 < TPW) {
            #pragma unroll
            for (int k = 0; k < 9; ++k) {
                const int mi = midx[i + 1][k];
                tbuf[nxt][k] = *(const float4*)(tokens + (size_t)(mi & 0x7fffffff) * DD + c0);
                sbuf[nxt][k] = (mi >= 0) ? 1.0f : 0.0f;
            }
        }
        float4 acc = bias4;
        #pragma unroll
        for (int k = 0; k < 9; ++k) {
            const float sel = sbuf[cur][k];
            acc.x += w4[k].x * (sel * tbuf[cur][k].x);
            acc.y += w4[k].y * (sel * tbuf[cur][k].y);
            acc.z += w4[k].z * (sel * tbuf[cur][k].z);
            acc.w += w4[k].w * (sel * tbuf[cur][k].w);
        }
        *(float4*)&s_out[wave * TPW + i][c0] = acc;
    }
    __syncthreads();

    // Thread ch gathers this block's 32 consecutive tokens for channel ch
    // and stores 128B contiguous at out[ch*N + n0].
    const int ch = threadIdx.x;
    float* dst = out + (size_t)ch * NTOK + blockIdx.x * TPB;
    #pragma unroll
    for (int j = 0; j < 8; ++j) {
        float4 v;
        v.x = s_out[4 * j + 0][ch];
        v.y = s_out[4 * j + 1][ch];
        v.z = s_out[4 * j + 2][ch];
        v.w = s_out[4 * j + 3][ch];
        *(float4*)(dst + 4 * j) = v;
    }
}

// ---------------------------------------------------------------------------
extern "C" void kernel_launch(void* const* d_in, const int* in_sizes, int n_in,
                              void* d_out, int out_size, void* d_ws, size_t ws_size,
                              hipStream_t stream)
{
    const float* tokens = (const float*)d_in[0];
    const int*   coords = (const int*)d_in[1];
    const float* weight = (const float*)d_in[2];
    const float* bias   = (const float*)d_in[3];
    float* out = (float*)d_out;

    // Workspace layout:
    //   [0, 9216)       wT: 9*256 fp32
    //   [9216, 10240)   biasf: 256 fp32
    //   [16384, 606208) pos_map: H*W int32
    char* ws = (char*)d_ws;
    float* wT      = (float*)ws;
    float* biasf   = (float*)(ws + 9216);
    int*   pos_map = (int*)(ws + 16384);

    hipMemsetAsync(pos_map, 0xFF, (size_t)HH * WW * sizeof(int), stream);
    prep_kernel<<<1, 256, 0, stream>>>(weight, bias, wT, biasf);
    scatter_pos_kernel<<<(NTOK + 255) / 256, 256, 0, stream>>>(coords, pos_map);
    conv_gather_kernel<<<NTOK / TPB, 256, 0, stream>>>(tokens, coords, wT, biasf,
                                                       pos_map, out);
}

// Round 8
// 164.830 us; speedup vs baseline: 1.8708x; 1.0651x over previous
//
#include <hip/hip_runtime.h>

// Semantics (verified through R0-R9 of previous session):
//   ABI: tokens (N,D) fp32, coords (N,2) int32, weight (D,1,3,3) fp32,
//   straight taps, straight scatter, zero padding/empty cells, bias added,
//   OUTPUT IS (D, N) flat (np advanced indexing, missing .T).
// R17: R2/R7 structure. New: invalid taps (avg ~4.45 of 9) no longer load
//   at all — the validity mask is wave-uniform (SGPR), so a scalar branch
//   skips the gather entirely. tbuf is zero-init so skipped entries hold a
//   stale-but-finite value that sel=0 annihilates. Halves VMEM request
//   count (9 -> ~4.55 gathers/token) to test the request-queue-bound
//   hypothesis (R2==R7 ruled out MLP-demand as the limit).
#define DD 256
#define HH 384
#define WW 384
#define NTOK 65536
#define TPB 32   // tokens per block
#define TPW 8    // tokens per wave

// ---------------------------------------------------------------------------
// Prep: weight (D,9) -> wT (9,D) (straight, no flip); bias copied.
// ---------------------------------------------------------------------------
__global__ __launch_bounds__(256) void prep_kernel(
    const float* __restrict__ weight, const float* __restrict__ bias,
    float* __restrict__ wT, float* __restrict__ biasf)
{
    int ch = threadIdx.x;  // 0..255
    #pragma unroll
    for (int k = 0; k < 9; ++k)
        wT[k * DD + ch] = weight[ch * 9 + k];
    biasf[ch] = bias[ch];
}

// ---------------------------------------------------------------------------
// Scatter (straight): pos_map[r*W + c] = token index (pre-filled with -1)
// ---------------------------------------------------------------------------
__global__ __launch_bounds__(256) void scatter_pos_kernel(
    const int* __restrict__ coords, int* __restrict__ pos_map)
{
    int n = blockIdx.x * blockDim.x + threadIdx.x;
    if (n < NTOK) {
        int r = coords[2 * n + 0];
        int c = coords[2 * n + 1];
        pos_map[r * WW + c] = n;
    }
}

// ---------------------------------------------------------------------------
// Main: 4 waves/block, 8 tokens per wave. Phase A: scalar (SMEM) loads of
// coords + all 72 pos_map entries (wave-uniform addresses). Phase B: 2-deep
// software-pipelined gather+FMA with scalar-branch load elision for
// invalid taps. Epilogue: 32KB LDS transpose; thread ch stores a full
// 128B line out[ch*N + n0 .. n0+31].
// ---------------------------------------------------------------------------
__global__ __launch_bounds__(256) void conv_gather_kernel(
    const float* __restrict__ tokens,
    const int*   __restrict__ coords,
    const float* __restrict__ wT,      // (9, D)
    const float* __restrict__ biasf,   // (D,)
    const int*   __restrict__ pos_map,
    float*       __restrict__ out)     // (D, N) layout!
{
    __shared__ float s_out[TPB][DD];            // 32 KB

    const int wave = threadIdx.x >> 6;          // 0..3
    const int lane = threadIdx.x & 63;
    const int c0   = lane * 4;
    // wave-uniform first token index, forced into SGPR
    const int nw   = __builtin_amdgcn_readfirstlane(blockIdx.x * TPB + wave * TPW);

    const float4 bias4 = *(const float4*)(biasf + c0);
    float4 w4[9];
    #pragma unroll
    for (int k = 0; k < 9; ++k)
        w4[k] = *(const float4*)(wT + k * DD + c0);

    // ---- Phase A: scalar loads. All addresses wave-uniform -> s_load. ----
    // midx holds token row (valid), or negative (invalid -> skip load).
    int midx[TPW][9];
    #pragma unroll
    for (int i = 0; i < TPW; ++i) {
        const int n = nw + i;
        const int r = coords[2 * n + 0];        // uniform -> s_load
        const int c = coords[2 * n + 1];
        #pragma unroll
        for (int dy = 0; dy < 3; ++dy) {
            #pragma unroll
            for (int dx = 0; dx < 3; ++dx) {
                const int k  = dy * 3 + dx;
                const int rr = r + dy - 1;
                const int cc = c + dx - 1;
                const bool in_bounds = (rr >= 0) & (rr < HH) & (cc >= 0) & (cc < WW);
                const int  pidx = in_bounds ? (rr * WW + cc) : 0;
                const int  m    = pos_map[pidx];    // uniform -> s_load
                midx[i][k] = in_bounds ? m : -1;    // m is -1 for empty cell
            }
        }
    }

    // ---- Phase B: 2-deep pipeline; loads elided for invalid taps. ----
    float4 tbuf[2][9];
    #pragma unroll
    for (int b = 0; b < 2; ++b)
        #pragma unroll
        for (int k = 0; k < 9; ++k)
            tbuf[b][k] = make_float4(0.f, 0.f, 0.f, 0.f);
    float sbuf[2][9];

    #pragma unroll
    for (int k = 0; k < 9; ++k) {
        const int mi = midx[0][k];
        sbuf[0][k] = (mi >= 0) ? 1.0f : 0.0f;
        if (mi >= 0)   // wave-uniform scalar branch
            tbuf[0][k] = *(const float4*)(tokens + (size_t)mi * DD + c0);
    }
    #pragma unroll
    for (int i = 0; i < TPW; ++i) {
        const int cur = i & 1;
        const int nxt = cur ^ 1;
        if (i + 1 < TPW) {
            #pragma unroll
            for (int k = 0; k < 9; ++k) {
                const int mi = midx[i + 1][k];
                sbuf[nxt][k] = (mi >= 0) ? 1.0f : 0.0f;
                if (mi >= 0)   // wave-uniform scalar branch
                    tbuf[nxt][k] = *(const float4*)(tokens + (size_t)mi * DD + c0);
            }
        }
        float4 acc = bias4;
        #pragma unroll
        for (int k = 0; k < 9; ++k) {
            const float sel = sbuf[cur][k];
            acc.x += w4[k].x * (sel * tbuf[cur][k].x);
            acc.y += w4[k].y * (sel * tbuf[cur][k].y);
            acc.z += w4[k].z * (sel * tbuf[cur][k].z);
            acc.w += w4[k].w * (sel * tbuf[cur][k].w);
        }
        *(float4*)&s_out[wave * TPW + i][c0] = acc;
    }
    __syncthreads();

    // Thread ch gathers this block's 32 consecutive tokens for channel ch
    // and stores 128B contiguous at out[ch*N + n0].
    const int ch = threadIdx.x;
    float* dst = out + (size_t)ch * NTOK + blockIdx.x * TPB;
    #pragma unroll
    for (int j = 0; j < 8; ++j) {
        float4 v;
        v.x = s_out[4 * j + 0][ch];
        v.y = s_out[4 * j + 1][ch];
        v.z = s_out[4 * j + 2][ch];
        v.w = s_out[4 * j + 3][ch];
        *(float4*)(dst + 4 * j) = v;
    }
}

// ---------------------------------------------------------------------------
extern "C" void kernel_launch(void* const* d_in, const int* in_sizes, int n_in,
                              void* d_out, int out_size, void* d_ws, size_t ws_size,
                              hipStream_t stream)
{
    const float* tokens = (const float*)d_in[0];
    const int*   coords = (const int*)d_in[1];
    const float* weight = (const float*)d_in[2];
    const float* bias   = (const float*)d_in[3];
    float* out = (float*)d_out;

    // Workspace layout:
    //   [0, 9216)       wT: 9*256 fp32
    //   [9216, 10240)   biasf: 256 fp32
    //   [16384, 606208) pos_map: H*W int32
    char* ws = (char*)d_ws;
    float* wT      = (float*)ws;
    float* biasf   = (float*)(ws + 9216);
    int*   pos_map = (int*)(ws + 16384);

    hipMemsetAsync(pos_map, 0xFF, (size_t)HH * WW * sizeof(int), stream);
    prep_kernel<<<1, 256, 0, stream>>>(weight, bias, wT, biasf);
    scatter_pos_kernel<<<(NTOK + 255) / 256, 256, 0, stream>>>(coords, pos_map);
    conv_gather_kernel<<<NTOK / TPB, 256, 0, stream>>>(tokens, coords, wT, biasf,
                                                       pos_map, out);
}

// Round 10
// 162.737 us; speedup vs baseline: 1.8949x; 1.0129x over previous
//
#include <hip/hip_runtime.h>

// Semantics (verified through R0-R9 of previous session):
//   ABI: tokens (N,D) fp32, coords (N,2) int32, weight (D,1,3,3) fp32,
//   straight taps, straight scatter, zero padding/empty cells, bias added,
//   OUTPUT IS (D, N) flat (np advanced indexing, missing .T).
// R19: R8 conv body verbatim (67.4us: load elision + 2-deep pipeline).
//   prep_kernel ELIMINATED: weights transposed in-register from the lane's
//   contiguous 144B slice (w4[k].x = weight[c0*9+k] == old wT[k*256+c0]).
//   3 dispatches (memset, scatter, conv). R9's cooperative fuse failed
//   (absmax 3.6 ~ output never written / pos_map invisible) — reverted.
//   This round isolates per-dispatch cost: e2e gap model says ~90us of the
//   164.8 is harness reset, ours is ~10; measure the delta.
#define DD 256
#define HH 384
#define WW 384
#define NTOK 65536
#define TPB 32   // tokens per block
#define TPW 8    // tokens per wave

// ---------------------------------------------------------------------------
// Scatter (straight): pos_map[r*W + c] = token index (pre-filled with -1)
// ---------------------------------------------------------------------------
__global__ __launch_bounds__(256) void scatter_pos_kernel(
    const int* __restrict__ coords, int* __restrict__ pos_map)
{
    int n = blockIdx.x * blockDim.x + threadIdx.x;
    if (n < NTOK) {
        int r = coords[2 * n + 0];
        int c = coords[2 * n + 1];
        pos_map[r * WW + c] = n;
    }
}

// ---------------------------------------------------------------------------
// Main: 4 waves/block, 8 tokens per wave. Weights transposed in-register
// (prep fused). Phase A: scalar (SMEM) loads of coords + all 72 pos_map
// entries (wave-uniform addresses). Phase B: 2-deep software-pipelined
// gather+FMA with scalar-branch load elision for invalid taps. Epilogue:
// 32KB LDS transpose; thread ch stores a full 128B line out[ch*N+n0..+31].
// ---------------------------------------------------------------------------
__global__ __launch_bounds__(256) void conv_gather_kernel(
    const float* __restrict__ tokens,
    const int*   __restrict__ coords,
    const float* __restrict__ weight,  // (D,1,3,3) = (D,9)
    const float* __restrict__ bias,    // (D,)
    const int*   __restrict__ pos_map,
    float*       __restrict__ out)     // (D, N) layout!
{
    __shared__ float s_out[TPB][DD];            // 32 KB

    const int wave = threadIdx.x >> 6;          // 0..3
    const int lane = threadIdx.x & 63;
    const int c0   = lane * 4;
    // wave-uniform first token index, forced into SGPR
    const int nw   = __builtin_amdgcn_readfirstlane(blockIdx.x * TPB + wave * TPW);

    // In-register weight transpose: lane's 4 channels = 36 contiguous
    // floats at weight[c0*9] (144B, 16B-aligned). w4[k] = tap k x 4 ch:
    //   w4[k].x = weight[c0*9 + k]       (== old wT[k*256 + c0])
    //   w4[k].y = weight[(c0+1)*9 + k]   (== old wT[k*256 + c0+1]) etc.
    float wr[36];
    #pragma unroll
    for (int i = 0; i < 9; ++i)
        *(float4*)&wr[4 * i] = *(const float4*)(weight + c0 * 9 + 4 * i);
    float4 w4[9];
    #pragma unroll
    for (int k = 0; k < 9; ++k)
        w4[k] = make_float4(wr[k], wr[9 + k], wr[18 + k], wr[27 + k]);
    const float4 bias4 = *(const float4*)(bias + c0);

    // ---- Phase A: scalar loads. All addresses wave-uniform -> s_load. ----
    // midx holds token row (valid), or negative (invalid -> skip load).
    int midx[TPW][9];
    #pragma unroll
    for (int i = 0; i < TPW; ++i) {
        const int n = nw + i;
        const int r = coords[2 * n + 0];        // uniform -> s_load
        const int c = coords[2 * n + 1];
        #pragma unroll
        for (int dy = 0; dy < 3; ++dy) {
            #pragma unroll
            for (int dx = 0; dx < 3; ++dx) {
                const int k  = dy * 3 + dx;
                const int rr = r + dy - 1;
                const int cc = c + dx - 1;
                const bool in_bounds = (rr >= 0) & (rr < HH) & (cc >= 0) & (cc < WW);
                const int  pidx = in_bounds ? (rr * WW + cc) : 0;
                const int  m    = pos_map[pidx];    // uniform -> s_load
                midx[i][k] = in_bounds ? m : -1;    // m is -1 for empty cell
            }
        }
    }

    // ---- Phase B: 2-deep pipeline; loads elided for invalid taps. ----
    float4 tbuf[2][9];
    #pragma unroll
    for (int b = 0; b < 2; ++b)
        #pragma unroll
        for (int k = 0; k < 9; ++k)
            tbuf[b][k] = make_float4(0.f, 0.f, 0.f, 0.f);
    float sbuf[2][9];

    #pragma unroll
    for (int k = 0; k < 9; ++k) {
        const int mi = midx[0][k];
        sbuf[0][k] = (mi >= 0) ? 1.0f : 0.0f;
        if (mi >= 0)   // wave-uniform scalar branch
            tbuf[0][k] = *(const float4*)(tokens + (size_t)mi * DD + c0);
    }
    #pragma unroll
    for (int i = 0; i < TPW; ++i) {
        const int cur = i & 1;
        const int nxt = cur ^ 1;
        if (i + 1 < TPW) {
            #pragma unroll
            for (int k = 0; k < 9; ++k) {
                const int mi = midx[i + 1][k];
                sbuf[nxt][k] = (mi >= 0) ? 1.0f : 0.0f;
                if (mi >= 0)   // wave-uniform scalar branch
                    tbuf[nxt][k] = *(const float4*)(tokens + (size_t)mi * DD + c0);
            }
        }
        float4 acc = bias4;
        #pragma unroll
        for (int k = 0; k < 9; ++k) {
            const float sel = sbuf[cur][k];
            acc.x += w4[k].x * (sel * tbuf[cur][k].x);
            acc.y += w4[k].y * (sel * tbuf[cur][k].y);
            acc.z += w4[k].z * (sel * tbuf[cur][k].z);
            acc.w += w4[k].w * (sel * tbuf[cur][k].w);
        }
        *(float4*)&s_out[wave * TPW + i][c0] = acc;
    }
    __syncthreads();

    // Thread ch gathers this block's 32 consecutive tokens for channel ch
    // and stores 128B contiguous at out[ch*N + n0].
    const int ch = threadIdx.x;
    float* dst = out + (size_t)ch * NTOK + blockIdx.x * TPB;
    #pragma unroll
    for (int j = 0; j < 8; ++j) {
        float4 v;
        v.x = s_out[4 * j + 0][ch];
        v.y = s_out[4 * j + 1][ch];
        v.z = s_out[4 * j + 2][ch];
        v.w = s_out[4 * j + 3][ch];
        *(float4*)(dst + 4 * j) = v;
    }
}

// ---------------------------------------------------------------------------
extern "C" void kernel_launch(void* const* d_in, const int* in_sizes, int n_in,
                              void* d_out, int out_size, void* d_ws, size_t ws_size,
                              hipStream_t stream)
{
    const float* tokens = (const float*)d_in[0];
    const int*   coords = (const int*)d_in[1];
    const float* weight = (const float*)d_in[2];
    const float* bias   = (const float*)d_in[3];
    float* out = (float*)d_out;

    // Workspace: pos_map only (H*W int32)
    int* pos_map = (int*)d_ws;

    hipMemsetAsync(pos_map, 0xFF, (size_t)HH * WW * sizeof(int), stream);
    scatter_pos_kernel<<<(NTOK + 255) / 256, 256, 0, stream>>>(coords, pos_map);
    conv_gather_kernel<<<NTOK / TPB, 256, 0, stream>>>(tokens, coords, weight,
                                                       bias, pos_map, out);
}